// Round 1
// baseline (697.479 us; speedup 1.0000x reference)
//
#include <hip/hip_runtime.h>
#include <stdint.h>

typedef unsigned short u16;
typedef __bf16 bf16x8 __attribute__((ext_vector_type(8)));
typedef float floatx4 __attribute__((ext_vector_type(4)));

#define TM 128
#define TN 128
#define BK 64

// ---------------- scalar init ----------------
__global__ void init_scalars_k(unsigned* s) {
    if (threadIdx.x < 2) s[threadIdx.x] = 0u;   // amax_x, amax_w slots
}

// ---------------- global amax ----------------
__global__ void amax_k(const float4* __restrict__ src, long n4, unsigned* slot) {
    float m = 0.0f;
    long stride = (long)gridDim.x * blockDim.x;
    for (long i = (long)blockIdx.x * blockDim.x + threadIdx.x; i < n4; i += stride) {
        float4 v = src[i];
        m = fmaxf(m, fmaxf(fmaxf(fabsf(v.x), fabsf(v.y)), fmaxf(fabsf(v.z), fabsf(v.w))));
    }
    #pragma unroll
    for (int off = 32; off > 0; off >>= 1)
        m = fmaxf(m, __shfl_down(m, off, 64));
    __shared__ float sm[4];
    int lane = threadIdx.x & 63, wv = threadIdx.x >> 6;
    if (lane == 0) sm[wv] = m;
    __syncthreads();
    if (threadIdx.x == 0) {
        m = fmaxf(fmaxf(sm[0], sm[1]), fmaxf(sm[2], sm[3]));
        atomicMax(slot, __float_as_uint(m));   // nonneg fp32: uint order == float order
    }
}

// ---------------- derived scales ----------------
// s[0..1]: amax bits; s[2]=gs_x s[3]=gs_w s[4]=gs_x/6 s[5]=gs_w/6 s[6]=alpha
__global__ void scales_k(float* s) {
    if (threadIdx.x != 0) return;
    float ax = __uint_as_float(((unsigned*)s)[0]);
    float aw = __uint_as_float(((unsigned*)s)[1]);
    float gsx = 2688.0f / ax;      // (448*6)/amax, fp32 like reference
    float gsw = 2688.0f / aw;
    s[2] = gsx; s[3] = gsw;
    s[4] = gsx / 6.0f; s[5] = gsw / 6.0f;   // reference computes gs/F4_MAX first
    s[6] = 1.0f / (gsx * gsw);
}

// ---------------- quantization helpers ----------------
// RNE float -> e4m3fn for v in [0, 448] (guaranteed by construction)
__device__ __forceinline__ float e4m3_rne(float v) {
    if (v < 0.015625f) return rintf(v * 512.0f) * 0.001953125f;  // subnormal, step 2^-9
    unsigned u = __float_as_uint(v);
    u += 0x7FFFFu + ((u >> 20) & 1u);      // RNE at 3 mantissa bits
    return __uint_as_float(u & 0xFFF00000u);
}

// RNE to fp4 e2m1 value set {0,±0.5,1,1.5,2,3,4,6}; mirrors reference clip->step->round
__device__ __forceinline__ float fp4_rne(float x) {
    float a = fminf(fabsf(x), 6.0f);
    float mul, step;
    if (a < 2.0f)      { mul = 2.0f; step = 0.5f; }
    else if (a < 4.0f) { mul = 1.0f; step = 1.0f; }
    else               { mul = 0.5f; step = 2.0f; }
    float q = fminf(rintf(a * mul) * step, 6.0f);   // rintf = round-half-even
    return copysignf(q, x);
}

// pack two fp32 (exactly representable in bf16) into 2 bf16 bit patterns
__device__ __forceinline__ unsigned pack2(float d0, float d1) {
    return (__float_as_uint(d0) >> 16) | (__float_as_uint(d1) & 0xFFFF0000u);
}

// One thread per 16-element block: emit q*scale_e4m3 as bf16 (exact).
__global__ void quant_k(const float* __restrict__ src, u16* __restrict__ dst,
                        const float* __restrict__ scal, int gsi, int ti, long nb) {
    long b = (long)blockIdx.x * blockDim.x + threadIdx.x;
    if (b >= nb) return;
    float gs = scal[gsi], t = scal[ti];
    const float4* p = (const float4*)(src + b * 16);
    float4 v0 = p[0], v1 = p[1], v2 = p[2], v3 = p[3];
    float am = 0.0f;
    am = fmaxf(am, fmaxf(fmaxf(fabsf(v0.x), fabsf(v0.y)), fmaxf(fabsf(v0.z), fabsf(v0.w))));
    am = fmaxf(am, fmaxf(fmaxf(fabsf(v1.x), fabsf(v1.y)), fmaxf(fabsf(v1.z), fabsf(v1.w))));
    am = fmaxf(am, fmaxf(fmaxf(fabsf(v2.x), fabsf(v2.y)), fmaxf(fabsf(v2.z), fabsf(v2.w))));
    am = fmaxf(am, fmaxf(fmaxf(fabsf(v3.x), fabsf(v3.y)), fmaxf(fabsf(v3.z), fabsf(v3.w))));
    float sf = e4m3_rne(am * t);                  // e4m3 block scale (as fp32)
    float r = gs / (sf > 0.0f ? sf : 1.0f);       // reference: gs/safe, then v*r
    uint4 o0, o1;
    o0.x = pack2(fp4_rne(v0.x * r) * sf, fp4_rne(v0.y * r) * sf);
    o0.y = pack2(fp4_rne(v0.z * r) * sf, fp4_rne(v0.w * r) * sf);
    o0.z = pack2(fp4_rne(v1.x * r) * sf, fp4_rne(v1.y * r) * sf);
    o0.w = pack2(fp4_rne(v1.z * r) * sf, fp4_rne(v1.w * r) * sf);
    o1.x = pack2(fp4_rne(v2.x * r) * sf, fp4_rne(v2.y * r) * sf);
    o1.y = pack2(fp4_rne(v2.z * r) * sf, fp4_rne(v2.w * r) * sf);
    o1.z = pack2(fp4_rne(v3.x * r) * sf, fp4_rne(v3.y * r) * sf);
    o1.w = pack2(fp4_rne(v3.z * r) * sf, fp4_rne(v3.w * r) * sf);
    uint4* q = (uint4*)(dst + b * 16);
    q[0] = o0; q[1] = o1;
}

// ---------------- GEMM: out[m][n] = alpha * sum_k A[m][k]*B[n][k] + bias[n] ----------------
// m97 structure: 128x128 tile, BK=64, 4 waves (2x2 of 64x64), 16x16x32 bf16 MFMA,
// global_load_lds width=16 with XOR-16B-chunk swizzle (c ^= row&7) for conflict-free ds_read_b128.
__global__ __launch_bounds__(256) void gemm_k(
    const u16* __restrict__ A, const u16* __restrict__ B,
    const float* __restrict__ bias, const float* __restrict__ scal,
    float* __restrict__ out, int M, int N, int K)
{
    __shared__ u16 As[TM * BK];
    __shared__ u16 Bs[TN * BK];
    const int tid  = threadIdx.x;
    const int lane = tid & 63;
    const int wv   = tid >> 6;
    const int tileM = blockIdx.y * TM;
    const int tileN = blockIdx.x * TN;
    const int wm = (wv >> 1) * 64;
    const int wn = (wv & 1) * 64;
    const int quad = lane >> 4;
    const int l16  = lane & 15;

    floatx4 acc[4][4] = {};

    const int srow_base = wv * 32;     // this wave stages rows [srow_base, srow_base+32)
    const int sr = lane >> 3;          // relative row within 8-row group
    const int sc = lane & 7;           // dest 16B chunk within row

    for (int k0 = 0; k0 < K; k0 += BK) {
        #pragma unroll
        for (int i = 0; i < 4; i++) {
            int r = srow_base + i * 8 + sr;
            int g = sc ^ (r & 7);      // swizzled source chunk
            const u16* ga = A + (size_t)(tileM + r) * K + k0 + g * 8;
            const u16* gb = B + (size_t)(tileN + r) * K + k0 + g * 8;
            __builtin_amdgcn_global_load_lds(
                (const __attribute__((address_space(1))) void*)ga,
                (__attribute__((address_space(3))) void*)(As + (srow_base + i * 8) * BK),
                16, 0, 0);
            __builtin_amdgcn_global_load_lds(
                (const __attribute__((address_space(1))) void*)gb,
                (__attribute__((address_space(3))) void*)(Bs + (srow_base + i * 8) * BK),
                16, 0, 0);
        }
        __syncthreads();
        #pragma unroll
        for (int ks = 0; ks < 2; ks++) {
            int gch = ks * 4 + quad;   // global k-chunk: k = gch*8 .. +8
            bf16x8 af[4], bfr[4];
            #pragma unroll
            for (int i = 0; i < 4; i++) {
                int m = wm + i * 16 + l16;
                af[i] = *(const bf16x8*)(As + m * BK + ((gch ^ (m & 7)) * 8));
                int n = wn + i * 16 + l16;
                bfr[i] = *(const bf16x8*)(Bs + n * BK + ((gch ^ (n & 7)) * 8));
            }
            #pragma unroll
            for (int i = 0; i < 4; i++)
                #pragma unroll
                for (int j = 0; j < 4; j++)
                    acc[i][j] = __builtin_amdgcn_mfma_f32_16x16x32_bf16(
                        af[i], bfr[j], acc[i][j], 0, 0, 0);
        }
        __syncthreads();
    }

    const float alpha = scal[6];
    #pragma unroll
    for (int j = 0; j < 4; j++) {
        int n = tileN + wn + j * 16 + l16;
        float bv = bias[n];
        #pragma unroll
        for (int i = 0; i < 4; i++) {
            int m0 = tileM + wm + i * 16 + quad * 4;   // C/D: row = quad*4+reg, col = lane&15
            #pragma unroll
            for (int rg = 0; rg < 4; rg++)
                out[(size_t)(m0 + rg) * N + n] = acc[i][j][rg] * alpha + bv;
        }
    }
}

// ---------------- launch ----------------
extern "C" void kernel_launch(void* const* d_in, const int* in_sizes, int n_in,
                              void* d_out, int out_size, void* d_ws, size_t ws_size,
                              hipStream_t stream) {
    const float* x    = (const float*)d_in[0];
    const float* W    = (const float*)d_in[1];
    const float* bias = (const float*)d_in[2];
    float* out = (float*)d_out;

    const int N = in_sizes[2];
    const int K = in_sizes[1] / N;
    const int M = in_sizes[0] / K;

    float* scal = (float*)d_ws;
    u16* Aq = (u16*)((char*)d_ws + 256);
    u16* Bq = (u16*)((char*)d_ws + 256 + (size_t)M * K * sizeof(u16));

    hipLaunchKernelGGL(init_scalars_k, dim3(1), dim3(64), 0, stream, (unsigned*)scal);
    hipLaunchKernelGGL(amax_k, dim3(2048), dim3(256), 0, stream,
                       (const float4*)x, (long)M * K / 4, (unsigned*)scal + 0);
    hipLaunchKernelGGL(amax_k, dim3(1024), dim3(256), 0, stream,
                       (const float4*)W, (long)N * K / 4, (unsigned*)scal + 1);
    hipLaunchKernelGGL(scales_k, dim3(1), dim3(64), 0, stream, scal);

    long nbx = (long)M * K / 16;
    long nbw = (long)N * K / 16;
    hipLaunchKernelGGL(quant_k, dim3((unsigned)((nbx + 255) / 256)), dim3(256), 0, stream,
                       x, Aq, scal, 2, 4, nbx);
    hipLaunchKernelGGL(quant_k, dim3((unsigned)((nbw + 255) / 256)), dim3(256), 0, stream,
                       W, Bq, scal, 3, 5, nbw);

    hipLaunchKernelGGL(gemm_k, dim3(N / TN, M / TM), dim3(256), 0, stream,
                       Aq, Bq, bias, scal, out, M, N, K);
}

// Round 2
// 593.048 us; speedup vs baseline: 1.1761x; 1.1761x over previous
//
#include <hip/hip_runtime.h>
#include <stdint.h>

typedef unsigned short u16;
typedef __bf16 bf16x8 __attribute__((ext_vector_type(8)));
typedef float floatx16 __attribute__((ext_vector_type(16)));

#define TM 128
#define TN 128
#define BK 64

// ---------------- fused global amax (x and W in one launch) ----------------
__global__ void amax_both_k(const float4* __restrict__ x, long nx4,
                            const float4* __restrict__ w, long nw4,
                            unsigned* slots, int gx) {
    const float4* src; long n4; int bid, nb; unsigned* slot;
    if ((int)blockIdx.x < gx) { src = x; n4 = nx4; bid = blockIdx.x; nb = gx; slot = slots; }
    else { src = w; n4 = nw4; bid = blockIdx.x - gx; nb = gridDim.x - gx; slot = slots + 1; }
    float m = 0.0f;
    long stride = (long)nb * blockDim.x;
    for (long i = (long)bid * blockDim.x + threadIdx.x; i < n4; i += stride) {
        float4 v = src[i];
        m = fmaxf(m, fmaxf(fmaxf(fabsf(v.x), fabsf(v.y)), fmaxf(fabsf(v.z), fabsf(v.w))));
    }
    #pragma unroll
    for (int off = 32; off > 0; off >>= 1)
        m = fmaxf(m, __shfl_down(m, off, 64));
    __shared__ float sm[4];
    int lane = threadIdx.x & 63, wv = threadIdx.x >> 6;
    if (lane == 0) sm[wv] = m;
    __syncthreads();
    if (threadIdx.x == 0) {
        m = fmaxf(fmaxf(sm[0], sm[1]), fmaxf(sm[2], sm[3]));
        atomicMax(slot, __float_as_uint(m));   // nonneg fp32: uint order == float order
    }
}

// ---------------- quantization helpers ----------------
// RNE float -> e4m3fn for v in [0, 448]
__device__ __forceinline__ float e4m3_rne(float v) {
    unsigned u = __float_as_uint(v);
    u += 0x7FFFFu + ((u >> 20) & 1u);            // RNE keep 3 mantissa bits
    float hi = __uint_as_float(u & 0xFFF00000u);
    float lo = rintf(v * 512.0f) * 0.001953125f; // subnormal, step 2^-9
    return (v < 0.015625f) ? lo : hi;
}

// RNE to fp4 e2m1 {0,±0.5,1,1.5,2,3,4,6}
__device__ __forceinline__ float fp4_rne(float x) {
    float a = fminf(fabsf(x), 6.0f);
    unsigned u = __float_as_uint(a);
    u += 0x1FFFFFu + ((u >> 22) & 1u);           // RNE keep 1 mantissa bit (a >= 1)
    float hi = __uint_as_float(u & 0xFFC00000u);
    float lo = rintf(a + a) * 0.5f;              // a < 1: fixed step 0.5
    float q = (a < 1.0f) ? lo : hi;
    return copysignf(q, x);
}

// pack two fp32 (exactly representable in bf16) into 2 bf16 bit patterns
__device__ __forceinline__ unsigned pack2(float d0, float d1) {
    return (__float_as_uint(d0) >> 16) | (__float_as_uint(d1) & 0xFFFF0000u);
}

// One thread per 16-elem nvfp4 block; handles both tensors in one launch.
__global__ void quant_both_k(const float* __restrict__ x, const float* __restrict__ W,
                             u16* __restrict__ Aq, u16* __restrict__ Bq,
                             const unsigned* __restrict__ slots, long nbx, long nbtot) {
    long b = (long)blockIdx.x * blockDim.x + threadIdx.x;
    if (b >= nbtot) return;
    const float* src; u16* dst; float ag;
    if (b < nbx) { src = x + b * 16; dst = Aq + b * 16; ag = __uint_as_float(slots[0]); }
    else { long c = b - nbx; src = W + c * 16; dst = Bq + c * 16; ag = __uint_as_float(slots[1]); }
    float gs = 2688.0f / ag;       // same fp32 ops as reference
    float t  = gs / 6.0f;          // reference computes gs/F4_MAX first
    const float4* p = (const float4*)src;
    float4 v0 = p[0], v1 = p[1], v2 = p[2], v3 = p[3];
    float am = 0.0f;
    am = fmaxf(am, fmaxf(fmaxf(fabsf(v0.x), fabsf(v0.y)), fmaxf(fabsf(v0.z), fabsf(v0.w))));
    am = fmaxf(am, fmaxf(fmaxf(fabsf(v1.x), fabsf(v1.y)), fmaxf(fabsf(v1.z), fabsf(v1.w))));
    am = fmaxf(am, fmaxf(fmaxf(fabsf(v2.x), fabsf(v2.y)), fmaxf(fabsf(v2.z), fabsf(v2.w))));
    am = fmaxf(am, fmaxf(fmaxf(fabsf(v3.x), fabsf(v3.y)), fmaxf(fabsf(v3.z), fabsf(v3.w))));
    float sf = e4m3_rne(am * t);
    float r = gs / (sf > 0.0f ? sf : 1.0f);      // reference: gs/safe, then v*r
    uint4 o0, o1;
    o0.x = pack2(fp4_rne(v0.x * r) * sf, fp4_rne(v0.y * r) * sf);
    o0.y = pack2(fp4_rne(v0.z * r) * sf, fp4_rne(v0.w * r) * sf);
    o0.z = pack2(fp4_rne(v1.x * r) * sf, fp4_rne(v1.y * r) * sf);
    o0.w = pack2(fp4_rne(v1.z * r) * sf, fp4_rne(v1.w * r) * sf);
    o1.x = pack2(fp4_rne(v2.x * r) * sf, fp4_rne(v2.y * r) * sf);
    o1.y = pack2(fp4_rne(v2.z * r) * sf, fp4_rne(v2.w * r) * sf);
    o1.z = pack2(fp4_rne(v3.x * r) * sf, fp4_rne(v3.y * r) * sf);
    o1.w = pack2(fp4_rne(v3.z * r) * sf, fp4_rne(v3.w * r) * sf);
    uint4* q = (uint4*)dst;
    q[0] = o0; q[1] = o1;
}

// ---------------- GEMM: out[m][n] = alpha * sum_k A[m][k]*B[n][k] + bias[n] ----------------
// 128x128 tile, BK=64, 4 waves (2x2 of 64x64), 32x32x16 bf16 MFMA (2x2 per wave),
// global_load_lds width=16 with XOR-16B-chunk swizzle (c ^= row&7): 0 bank conflicts (R1).
__global__ __launch_bounds__(256) void gemm_k(
    const u16* __restrict__ A, const u16* __restrict__ B,
    const float* __restrict__ bias, const unsigned* __restrict__ scal,
    float* __restrict__ out, int M, int N, int K)
{
    __shared__ u16 As[TM * BK];
    __shared__ u16 Bs[TN * BK];
    const int tid  = threadIdx.x;
    const int lane = tid & 63;
    const int wv   = tid >> 6;
    const int tileM = blockIdx.y * TM;
    const int tileN = blockIdx.x * TN;
    const int wm = (wv >> 1) * 64;
    const int wn = (wv & 1) * 64;
    const int r32  = lane & 31;
    const int half = lane >> 5;

    floatx16 acc[2][2] = {};

    const int srow_base = wv * 32;     // this wave stages rows [srow_base, srow_base+32)
    const int sr = lane >> 3;
    const int sc = lane & 7;

    for (int k0 = 0; k0 < K; k0 += BK) {
        #pragma unroll
        for (int i = 0; i < 4; i++) {
            int r = srow_base + i * 8 + sr;
            int g = sc ^ (r & 7);      // swizzled source chunk
            const u16* ga = A + (size_t)(tileM + r) * K + k0 + g * 8;
            const u16* gb = B + (size_t)(tileN + r) * K + k0 + g * 8;
            __builtin_amdgcn_global_load_lds(
                (const __attribute__((address_space(1))) void*)ga,
                (__attribute__((address_space(3))) void*)(As + (srow_base + i * 8) * BK),
                16, 0, 0);
            __builtin_amdgcn_global_load_lds(
                (const __attribute__((address_space(1))) void*)gb,
                (__attribute__((address_space(3))) void*)(Bs + (srow_base + i * 8) * BK),
                16, 0, 0);
        }
        __syncthreads();
        #pragma unroll
        for (int t = 0; t < 4; t++) {          // 4 k-steps of 16
            int ch = t * 2 + half;             // A/B frag: [row=lane&31][k=(lane>>5)*8+j]
            bf16x8 af[2], bfr[2];
            #pragma unroll
            for (int i = 0; i < 2; i++) {
                int m = wm + i * 32 + r32;
                af[i] = *(const bf16x8*)(As + m * BK + ((ch ^ (m & 7)) * 8));
                int n = wn + i * 32 + r32;
                bfr[i] = *(const bf16x8*)(Bs + n * BK + ((ch ^ (n & 7)) * 8));
            }
            #pragma unroll
            for (int i = 0; i < 2; i++)
                #pragma unroll
                for (int j = 0; j < 2; j++)
                    acc[i][j] = __builtin_amdgcn_mfma_f32_32x32x16_bf16(
                        af[i], bfr[j], acc[i][j], 0, 0, 0);
        }
        __syncthreads();
    }

    float ax = __uint_as_float(scal[0]);
    float aw = __uint_as_float(scal[1]);
    float gsx = 2688.0f / ax, gsw = 2688.0f / aw;
    float alpha = 1.0f / (gsx * gsw);

    // C/D (m74/m101): col = lane&31, row = (reg&3) + 8*(reg>>2) + 4*(lane>>5)
    #pragma unroll
    for (int j = 0; j < 2; j++) {
        int n = tileN + wn + j * 32 + r32;
        float bv = bias[n];
        #pragma unroll
        for (int i = 0; i < 2; i++) {
            int mbase = tileM + wm + i * 32 + half * 4;
            #pragma unroll
            for (int reg = 0; reg < 16; reg++) {
                int row = (reg & 3) + 8 * (reg >> 2);
                out[(size_t)(mbase + row) * N + n] = acc[i][j][reg] * alpha + bv;
            }
        }
    }
}

// ---------------- launch ----------------
extern "C" void kernel_launch(void* const* d_in, const int* in_sizes, int n_in,
                              void* d_out, int out_size, void* d_ws, size_t ws_size,
                              hipStream_t stream) {
    const float* x    = (const float*)d_in[0];
    const float* W    = (const float*)d_in[1];
    const float* bias = (const float*)d_in[2];
    float* out = (float*)d_out;

    const int N = in_sizes[2];
    const int K = in_sizes[1] / N;
    const int M = in_sizes[0] / K;

    unsigned* scal = (unsigned*)d_ws;
    u16* Aq = (u16*)((char*)d_ws + 256);
    u16* Bq = Aq + (size_t)M * K;

    hipMemsetAsync(scal, 0, 8, stream);

    const int GX = 2048, GW = 1024;
    hipLaunchKernelGGL(amax_both_k, dim3(GX + GW), dim3(256), 0, stream,
                       (const float4*)x, (long)M * K / 4,
                       (const float4*)W, (long)N * K / 4, scal, GX);

    long nbx = (long)M * K / 16;
    long nbw = (long)N * K / 16;
    hipLaunchKernelGGL(quant_both_k, dim3((unsigned)((nbx + nbw + 255) / 256)), dim3(256), 0, stream,
                       x, W, Aq, Bq, scal, nbx, nbx + nbw);

    hipLaunchKernelGGL(gemm_k, dim3(N / TN, M / TM), dim3(256), 0, stream,
                       Aq, Bq, bias, scal, out, M, N, K);
}